// Round 1
// baseline (2837.550 us; speedup 1.0000x reference)
//
#include <hip/hip_runtime.h>
#include <math.h>

#define NPTS  8192
#define DIM   512
#define KNNK  15
#define NPAIR 105

#define ITILE 16
#define JTILE 512
#define KC    32
#define BSTRIDE 513   // padded LDS row stride (floats) to break bank conflicts

#define CINF  3.0e38f

static __device__ __forceinline__ float wave_sum_f(float v) {
#pragma unroll
  for (int m = 32; m > 0; m >>= 1) v += __shfl_xor(v, m, 64);
  return v;
}

// ---------------------------------------------------------------- kernel 1
__global__ __launch_bounds__(256) void sqn_kernel(const float* __restrict__ E,
                                                  float* __restrict__ sqn) {
  const int row  = blockIdx.x * 4 + (threadIdx.x >> 6);
  const int lane = threadIdx.x & 63;
  float s = 0.f;
#pragma unroll
  for (int c = 0; c < 8; ++c) {
    float x = E[(size_t)row * DIM + lane + 64 * c];
    s = fmaf(x, x, s);
  }
  s = wave_sum_f(s);
  if (lane == 0) sqn[row] = s;
}

// ---------------------------------------------------------------- kernel 2
// One block handles ITILE=16 rows; loops over all j in tiles of 512.
// Thread GEMM tile: 4 i x 8 j.  Private per-thread top-16 over a disjoint
// j-subset (thread = (row, slot) with 16 slots/row), merged at the end.
__global__ __launch_bounds__(256, 2) void knn_kernel(
    const float* __restrict__ E, const float* __restrict__ sqn,
    float* __restrict__ okd, int* __restrict__ oki) {
  __shared__ float As[KC * ITILE];      // [k][i]
  __shared__ float Bs[KC * BSTRIDE];    // [k][j] padded; aliased below
  __shared__ float sqni[ITILE];

  const int tid = threadIdx.x;
  const int ty  = tid >> 6;   // 0..3  (wave id)
  const int tx  = tid & 63;   // lane
  const int tr  = tid >> 4;   // top-k row 0..15
  const int ts  = tid & 15;   // top-k slot 0..15
  const int i0  = blockIdx.x * ITILE;

  float td[16];
  int   tj[16];
#pragma unroll
  for (int p = 0; p < 16; ++p) { td[p] = CINF; tj[p] = -1; }

  if (tid < ITILE) sqni[tid] = sqn[i0 + tid];
  __syncthreads();

  const int iself = i0 + tr;

  for (int j0 = 0; j0 < NPTS; j0 += JTILE) {
    float acc[4][8];
#pragma unroll
    for (int ii = 0; ii < 4; ++ii)
#pragma unroll
      for (int u = 0; u < 8; ++u) acc[ii][u] = 0.f;

    for (int k0 = 0; k0 < DIM; k0 += KC) {
      // ---- stage A tile: [KC][ITILE]  (512 floats)
#pragma unroll
      for (int r = 0; r < 2; ++r) {
        int lin = tid + r * 256;            // 0..511
        int kk = lin >> 4, ii = lin & 15;
        As[kk * ITILE + ii] = E[(size_t)(i0 + ii) * DIM + k0 + kk];
      }
      // ---- stage B tile: rows j0..j0+511, cols k0..k0+31 -> [k][j] padded
#pragma unroll
      for (int it = 0; it < 16; ++it) {
        int lin = it * 256 + tid;           // 0..4095, 4 floats each
        int row = lin >> 3;                 // 0..511
        int kq  = (lin & 7) << 2;           // 0,4,..,28
        const float4 v = *(const float4*)&E[(size_t)(j0 + row) * DIM + k0 + kq];
        Bs[(kq + 0) * BSTRIDE + row] = v.x;
        Bs[(kq + 1) * BSTRIDE + row] = v.y;
        Bs[(kq + 2) * BSTRIDE + row] = v.z;
        Bs[(kq + 3) * BSTRIDE + row] = v.w;
      }
      __syncthreads();
      // ---- FMA: per k: 1 b128 (A, broadcast) + 8 b32 (B, 2-way) + 32 fma
#pragma unroll
      for (int kk = 0; kk < KC; ++kk) {
        const float4 a4 = *(const float4*)&As[kk * ITILE + ty * 4];
        float b[8];
#pragma unroll
        for (int u = 0; u < 8; ++u) b[u] = Bs[kk * BSTRIDE + tx + 64 * u];
#pragma unroll
        for (int u = 0; u < 8; ++u) {
          acc[0][u] = fmaf(a4.x, b[u], acc[0][u]);
          acc[1][u] = fmaf(a4.y, b[u], acc[1][u]);
          acc[2][u] = fmaf(a4.z, b[u], acc[2][u]);
          acc[3][u] = fmaf(a4.w, b[u], acc[3][u]);
        }
      }
      __syncthreads();
    }

    // ---- distances -> LDS (alias Bs): dist[16][512]
#pragma unroll
    for (int ii = 0; ii < 4; ++ii) {
      const float si = sqni[ty * 4 + ii];
#pragma unroll
      for (int u = 0; u < 8; ++u) {
        const int jl = tx + 64 * u;
        float dist = si + sqn[j0 + jl] - 2.0f * acc[ii][u];
        dist = fmaxf(dist, 0.0f);
        Bs[(ty * 4 + ii) * JTILE + jl] = dist;
      }
    }
    __syncthreads();

    // ---- candidate scan: thread (tr,ts) handles j = ts + 16*q
    for (int q = 0; q < 32; ++q) {
      const int jl = ts + 16 * q;
      const float dd = Bs[tr * JTILE + jl];
      const int jg = j0 + jl;
      if (jg != iself && dd < td[15]) {
        float cd = dd; int cj = jg;
#pragma unroll
        for (int p = 0; p < 16; ++p) {
          if (cd < td[p]) {
            float ft = td[p]; td[p] = cd; cd = ft;
            int it2 = tj[p]; tj[p] = cj; cj = it2;
          }
        }
      }
    }
    __syncthreads();
  }

  // ---- merge: dump 16 rows x 256 candidates, extract-min x15 per row
  float* md = Bs;                 // 4096 floats
  int*   mi = (int*)(Bs + 4096);  // 4096 ints
#pragma unroll
  for (int p = 0; p < 16; ++p) {
    md[tr * 256 + ts * 16 + p] = td[p];
    mi[tr * 256 + ts * 16 + p] = tj[p];
  }
  __syncthreads();

  for (int r = ty; r < ITILE; r += 4) {
    const float4 cv = *(const float4*)&md[r * 256 + tx * 4];
    float c0 = cv.x, c1 = cv.y, c2 = cv.z, c3 = cv.w;
    for (int sel = 0; sel < KNNK; ++sel) {
      float v = c0; int q = 0;
      if (c1 < v) { v = c1; q = 1; }
      if (c2 < v) { v = c2; q = 2; }
      if (c3 < v) { v = c3; q = 3; }
      int slot = tx * 4 + q;
#pragma unroll
      for (int off = 32; off > 0; off >>= 1) {
        float ov  = __shfl_down(v, off, 64);
        int   osl = __shfl_down(slot, off, 64);
        if (ov < v) { v = ov; slot = osl; }
      }
      const float vmin = __shfl(v, 0, 64);
      const int   smin = __shfl(slot, 0, 64);
      if (tx == (smin >> 2)) {
        const int qq = smin & 3;
        if (qq == 0) c0 = CINF; else if (qq == 1) c1 = CINF;
        else if (qq == 2) c2 = CINF; else c3 = CINF;
      }
      if (tx == 0) {
        okd[(i0 + r) * KNNK + sel] = sqrtf(fmaxf(vmin, 1e-12f));
        oki[(i0 + r) * KNNK + sel] = mi[r * 256 + smin];
      }
    }
  }
}

// ---------------------------------------------------------------- kernel 3
__global__ __launch_bounds__(256) void sig_kernel(
    const float* __restrict__ E, const float* __restrict__ kd,
    const int* __restrict__ ki, const float* __restrict__ refc,
    const float* __restrict__ refa, double* __restrict__ acc) {
  __shared__ float ei[DIM];
  __shared__ float vh[KNNK * DIM];
  __shared__ float cosb[128];
  __shared__ float red[4];
  __shared__ float curvs;

  const int i    = blockIdx.x;
  const int tid  = threadIdx.x;
  const int wid  = tid >> 6;
  const int lane = tid & 63;

  // stage e_i
  for (int c = tid; c < DIM; c += 256) ei[c] = E[(size_t)i * DIM + c];

  // curvature part (wave 0)
  if (wid == 0) {
    float d = (lane < KNNK) ? kd[i * KNNK + lane] : 0.f;
    float tot = wave_sum_f(d);
    float mean_d = tot / (float)KNNK + 1e-8f;
    float diff = 0.f;
    if (lane < KNNK) diff = d / mean_d - refc[i * KNNK + lane];
    float cs = wave_sum_f(diff * diff);
    if (lane == 0) curvs = cs;
  }
  __syncthreads();

  // normalized neighbor vectors
  for (int k = wid; k < KNNK; k += 4) {
    const int nb = ki[i * KNNK + k];
    float v[8];
    float ss = 0.f;
#pragma unroll
    for (int c = 0; c < 8; ++c) {
      const int d0 = lane + 64 * c;
      v[c] = E[(size_t)nb * DIM + d0] - ei[d0];
      ss = fmaf(v[c], v[c], ss);
    }
    ss = wave_sum_f(ss);
    const float inv = 1.0f / fmaxf(sqrtf(ss), 1e-8f);
#pragma unroll
    for (int c = 0; c < 8; ++c) vh[k * DIM + lane + 64 * c] = v[c] * inv;
  }
  __syncthreads();

  // 105 pairwise cosines
  for (int p = wid; p < NPAIR; p += 4) {
    int a = 0, pp = p, cnt = 14;
    while (pp >= cnt) { pp -= cnt; cnt--; a++; }
    const int b = a + 1 + pp;
    float s = 0.f;
#pragma unroll
    for (int c = 0; c < 8; ++c) {
      const int d0 = lane + 64 * c;
      s = fmaf(vh[a * DIM + d0], vh[b * DIM + d0], s);
    }
    s = wave_sum_f(s);
    if (lane == 0) cosb[p] = s;
  }
  if (tid < 128 - NPAIR) cosb[NPAIR + tid] = CINF;
  __syncthreads();

  // bitonic sort 128 ascending
  for (int k = 2; k <= 128; k <<= 1) {
    for (int j = k >> 1; j > 0; j >>= 1) {
      if (tid < 128) {
        const int ixj = tid ^ j;
        if (ixj > tid) {
          const bool up = ((tid & k) == 0);
          const float x = cosb[tid], y = cosb[ixj];
          if ((x > y) == up) { cosb[tid] = y; cosb[ixj] = x; }
        }
      }
      __syncthreads();
    }
  }

  // angular loss
  float part = 0.f;
  if (tid < NPAIR) {
    const float dd = cosb[tid] - refa[(size_t)i * NPAIR + tid];
    part = dd * dd;
  }
  part = wave_sum_f(part);
  if (lane == 0) red[wid] = part;
  __syncthreads();
  if (tid == 0) {
    const float ang = red[0] + red[1] + red[2] + red[3];
    atomicAdd(&acc[0], (double)curvs);
    atomicAdd(&acc[1], (double)ang);
  }
}

// ---------------------------------------------------------------- kernel 4
__global__ void fin_kernel(const double* __restrict__ acc,
                           float* __restrict__ out) {
  if (threadIdx.x == 0 && blockIdx.x == 0) {
    const double curv = acc[0] / ((double)NPTS * (double)KNNK);
    const double ang  = acc[1] / ((double)NPTS * (double)NPAIR);
    out[0] = (float)(0.3 * curv + 0.7 * ang);
  }
}

// ---------------------------------------------------------------- launch
extern "C" void kernel_launch(void* const* d_in, const int* in_sizes, int n_in,
                              void* d_out, int out_size, void* d_ws,
                              size_t ws_size, hipStream_t stream) {
  const float* E    = (const float*)d_in[0];
  const float* refc = (const float*)d_in[1];
  const float* refa = (const float*)d_in[2];
  float* out = (float*)d_out;

  char* ws = (char*)d_ws;
  double* acc = (double*)ws;                                   // 16 B
  float* sqn  = (float*)(ws + 256);                            // 32 KB
  float* kd   = (float*)(ws + 256 + NPTS * 4);                 // 480 KB
  int*   ki   = (int*)(ws + 256 + NPTS * 4 + NPTS * KNNK * 4); // 480 KB

  hipMemsetAsync(ws, 0, 16, stream);
  sqn_kernel<<<NPTS / 4, 256, 0, stream>>>(E, sqn);
  knn_kernel<<<NPTS / ITILE, 256, 0, stream>>>(E, sqn, kd, ki);
  sig_kernel<<<NPTS, 256, 0, stream>>>(E, kd, ki, refc, refa, acc);
  fin_kernel<<<1, 64, 0, stream>>>(acc, out);
}

// Round 2
// 760.990 us; speedup vs baseline: 3.7288x; 3.7288x over previous
//
#include <hip/hip_runtime.h>
#include <hip/hip_bf16.h>
#include <math.h>

#define NPTS  8192
#define DIM   512
#define KNNK  15
#define NPAIR 105
#define CINF  3.0e38f

#define NI      128            // i rows per block
#define NJSPLIT 8              // j splits (grid.y)
#define NJ      (NPTS/NJSPLIT) // 1024 j columns per block
#define JS      128            // j subtile
#define NSUB    (NJ/JS)        // 8
#define BK      32             // k chunk
#define NCH     (DIM/BK)       // 16
#define DSTRIDE 136            // dist LDS row stride (floats): bank=(2*row+col)%32 -> uniform 2-way (free)

typedef __attribute__((ext_vector_type(8))) short short8;
typedef __attribute__((ext_vector_type(4))) float f32x4;

static __device__ __forceinline__ float wave_sum_f(float v) {
#pragma unroll
  for (int m = 32; m > 0; m >>= 1) v += __shfl_xor(v, m, 64);
  return v;
}

static __device__ __forceinline__ void load_lds16(const void* g, void* l) {
  __builtin_amdgcn_global_load_lds(
      (const __attribute__((address_space(1))) void*)g,
      (__attribute__((address_space(3))) void*)l, 16, 0, 0);
}

// ---------------------------------------------------------------- prep
// sqn (fp32) + split E into bf16 hi/lo.
__global__ __launch_bounds__(256) void prep_kernel(
    const float* __restrict__ E, float* __restrict__ sqn,
    ushort* __restrict__ Ehi, ushort* __restrict__ Elo) {
  const int row  = blockIdx.x * 4 + (threadIdx.x >> 6);
  const int lane = threadIdx.x & 63;
  float s = 0.f;
#pragma unroll
  for (int c = 0; c < 8; ++c) {
    const int d0 = lane + 64 * c;
    const float x = E[(size_t)row * DIM + d0];
    s = fmaf(x, x, s);
    __hip_bfloat16 h = __float2bfloat16(x);
    const float hf = __bfloat162float(h);
    __hip_bfloat16 l = __float2bfloat16(x - hf);
    Ehi[(size_t)row * DIM + d0] = *(ushort*)&h;
    Elo[(size_t)row * DIM + d0] = *(ushort*)&l;
  }
  s = wave_sum_f(s);
  if (lane == 0) sqn[row] = s;
}

// ---------------------------------------------------------------- knn
// Block: 128 i-rows x 1024 j-cols (split blockIdx.y). MFMA split-bf16 GEMM:
// dot = hi*hi + hi*lo + lo*hi. Per j-subtile of 128: K-loop (16 chunks of 32),
// dist -> LDS, per-thread top-16 scan, then per-(row,split) top-15 to global.
__global__ __launch_bounds__(256, 2) void knn_kernel(
    const ushort* __restrict__ Ehi, const ushort* __restrict__ Elo,
    const float* __restrict__ sqn,
    float* __restrict__ cd, int* __restrict__ ci) {
  __shared__ __align__(16) char sm[DSTRIDE * 128 * 4 + 640];
  float* sdist = (float*)sm;                       // [128][DSTRIDE], aliases staging
  float* exi   = (float*)(sm + DSTRIDE * 128 * 4); // sqn_i[128]

  const int tid = threadIdx.x;
  const int w   = tid >> 6;   // wave 0..3
  const int L   = tid & 63;
  const int wr  = w >> 1;     // wave row quadrant
  const int wc  = w & 1;      // wave col half
  const int i0  = blockIdx.x * NI;
  const int j0  = blockIdx.y * NJ;

  if (tid < NI) exi[tid] = sqn[i0 + tid];

  float td[16];
  int   tj[16];
#pragma unroll
  for (int p = 0; p < 16; ++p) { td[p] = CINF; tj[p] = -1; }

  const int myrow = tid >> 1;       // scan row 0..127
  const int gi    = i0 + myrow;

  // staging role: wave w stages tile w: 0=A_hi 1=A_lo 2=B_hi 3=B_lo
  const ushort* srcBase = (w == 0 || w == 2) ? Ehi : Elo;
  char* ldsTileBase = sm + w * 8192;
  const int lrow = L >> 2;          // row-within-segment 0..15
  const int lk8  = (L & 3) * 8;     // k (ushort) offset within row

  const ushort* sAhi = (const ushort*)sm;
  const ushort* sAlo = (const ushort*)(sm + 8192);
  const ushort* sBhi = (const ushort*)(sm + 16384);
  const ushort* sBlo = (const ushort*)(sm + 24576);

  for (int js = 0; js < NSUB; ++js) {
    const int jrow0 = j0 + js * JS;
    const int trow0 = (w < 2) ? i0 : jrow0;   // tile source row base

    f32x4 acc[4][4];
#pragma unroll
    for (int fr = 0; fr < 4; ++fr)
#pragma unroll
      for (int fc = 0; fc < 4; ++fc)
#pragma unroll
        for (int r = 0; r < 4; ++r) acc[fr][fc][r] = 0.f;

    for (int ch = 0; ch < NCH; ++ch) {
      const int k0 = ch * BK;
      __syncthreads();   // staging region free (prev chunk reads / prev scan done)
#pragma unroll
      for (int s = 0; s < 8; ++s) {
        const ushort* gp = srcBase + (size_t)(trow0 + s * 16 + lrow) * DIM + k0 + lk8;
        load_lds16(gp, ldsTileBase + s * 1024);
      }
      __syncthreads();   // drains vmcnt: staged tiles visible

      short8 ah[4], al[4], bh[4], bl[4];
      const int q16 = (L >> 4) * 8;
#pragma unroll
      for (int f = 0; f < 4; ++f) {
        const int ra = wr * 64 + f * 16 + (L & 15);
        ah[f] = *(const short8*)&sAhi[ra * BK + q16];
        al[f] = *(const short8*)&sAlo[ra * BK + q16];
        const int rb = wc * 64 + f * 16 + (L & 15);
        bh[f] = *(const short8*)&sBhi[rb * BK + q16];
        bl[f] = *(const short8*)&sBlo[rb * BK + q16];
      }
#pragma unroll
      for (int fr = 0; fr < 4; ++fr)
#pragma unroll
        for (int fc = 0; fc < 4; ++fc) {
          acc[fr][fc] = __builtin_amdgcn_mfma_f32_16x16x32_bf16(ah[fr], bh[fc], acc[fr][fc], 0, 0, 0);
          acc[fr][fc] = __builtin_amdgcn_mfma_f32_16x16x32_bf16(ah[fr], bl[fc], acc[fr][fc], 0, 0, 0);
          acc[fr][fc] = __builtin_amdgcn_mfma_f32_16x16x32_bf16(al[fr], bh[fc], acc[fr][fc], 0, 0, 0);
        }
    }
    __syncthreads();   // all waves done reading staging; sdist may be written

    // ---- distances -> LDS
    float sqj[4];
#pragma unroll
    for (int fc = 0; fc < 4; ++fc)
      sqj[fc] = sqn[jrow0 + wc * 64 + fc * 16 + (L & 15)];
#pragma unroll
    for (int fr = 0; fr < 4; ++fr)
#pragma unroll
      for (int fc = 0; fc < 4; ++fc)
#pragma unroll
        for (int r = 0; r < 4; ++r) {
          const int row_l = wr * 64 + fr * 16 + (L >> 4) * 4 + r;
          const int col_l = wc * 64 + fc * 16 + (L & 15);
          const float d = exi[row_l] + sqj[fc] - 2.0f * acc[fr][fc][r];
          sdist[row_l * DSTRIDE + col_l] = fmaxf(d, 0.f);
        }
    __syncthreads();

    // ---- scan: thread (row=tid>>1) scans cols (tid&1)+2q
    const int c0 = tid & 1;
    for (int q = 0; q < 64; ++q) {
      const int cl = c0 + 2 * q;
      const float dd = sdist[myrow * DSTRIDE + cl];
      const int gj = jrow0 + cl;
      if (gj != gi && dd < td[15]) {
        float cdv = dd; int cjv = gj;
#pragma unroll
        for (int p = 0; p < 16; ++p) {
          if (cdv < td[p]) {
            const float ft = td[p]; td[p] = cdv; cdv = ft;
            const int it2 = tj[p]; tj[p] = cjv; cjv = it2;
          }
        }
      }
    }
  }
  __syncthreads();

  // ---- pair-merge the two half-scans of each row -> top-15 per (row, split)
  float* md  = sdist;               // [128][2][16] floats (16 KB)
  int*   mi_ = (int*)(sm + 16384);  // [128][2][16] ints (16 KB)
#pragma unroll
  for (int p = 0; p < 16; ++p) {
    md[(myrow * 2 + (tid & 1)) * 16 + p]  = td[p];
    mi_[(myrow * 2 + (tid & 1)) * 16 + p] = tj[p];
  }
  __syncthreads();
  if ((tid & 1) == 0) {
    const float* da = &md[(myrow * 2 + 0) * 16];
    const float* db = &md[(myrow * 2 + 1) * 16];
    const int*   ia = &mi_[(myrow * 2 + 0) * 16];
    const int*   ib = &mi_[(myrow * 2 + 1) * 16];
    int pa = 0, pb = 0;
    const size_t base = ((size_t)gi * NJSPLIT + blockIdx.y) * KNNK;
    for (int s2 = 0; s2 < KNNK; ++s2) {
      const float va = da[pa], vb = db[pb];
      if (va <= vb) { cd[base + s2] = va; ci[base + s2] = ia[pa]; ++pa; }
      else          { cd[base + s2] = vb; ci[base + s2] = ib[pb]; ++pb; }
    }
  }
}

// ---------------------------------------------------------------- merge
// Final top-15 per row from 8 splits x 15 candidates (120).
__global__ __launch_bounds__(256) void kmerge_kernel(
    const float* __restrict__ cd, const int* __restrict__ ci,
    float* __restrict__ kd, int* __restrict__ ki) {
  const int row = blockIdx.x * 4 + (threadIdx.x >> 6);
  const int L   = threadIdx.x & 63;
  const size_t base = (size_t)row * (NJSPLIT * KNNK);
  float v0 = (L < 120)      ? cd[base + L]      : CINF;
  float v1 = (L + 64 < 120) ? cd[base + L + 64] : CINF;
  int   i0v = (L < 120)      ? ci[base + L]      : -1;
  int   i1v = (L + 64 < 120) ? ci[base + L + 64] : -1;
  for (int sel = 0; sel < KNNK; ++sel) {
    float v; int idx, slot;
    if (v1 < v0) { v = v1; idx = i1v; slot = (L << 1) | 1; }
    else         { v = v0; idx = i0v; slot = (L << 1); }
#pragma unroll
    for (int off = 32; off > 0; off >>= 1) {
      const float ov = __shfl_down(v, off, 64);
      const int   oi = __shfl_down(idx, off, 64);
      const int   os = __shfl_down(slot, off, 64);
      if (ov < v) { v = ov; idx = oi; slot = os; }
    }
    const float vmin = __shfl(v, 0, 64);
    const int   imin = __shfl(idx, 0, 64);
    const int   smin = __shfl(slot, 0, 64);
    if (L == (smin >> 1)) { if (smin & 1) v1 = CINF; else v0 = CINF; }
    if (L == 0) {
      kd[row * KNNK + sel] = sqrtf(fmaxf(vmin, 1e-12f));
      ki[row * KNNK + sel] = imin;
    }
  }
}

// ---------------------------------------------------------------- sig
__global__ __launch_bounds__(256) void sig_kernel(
    const float* __restrict__ E, const float* __restrict__ kd,
    const int* __restrict__ ki, const float* __restrict__ refc,
    const float* __restrict__ refa, double* __restrict__ acc) {
  __shared__ float ei[DIM];
  __shared__ float vh[KNNK * DIM];
  __shared__ float cosb[128];
  __shared__ float red[4];
  __shared__ float curvs;

  const int i    = blockIdx.x;
  const int tid  = threadIdx.x;
  const int wid  = tid >> 6;
  const int lane = tid & 63;

  for (int c = tid; c < DIM; c += 256) ei[c] = E[(size_t)i * DIM + c];

  if (wid == 0) {
    float d = (lane < KNNK) ? kd[i * KNNK + lane] : 0.f;
    float tot = wave_sum_f(d);
    float mean_d = tot / (float)KNNK + 1e-8f;
    float diff = 0.f;
    if (lane < KNNK) diff = d / mean_d - refc[i * KNNK + lane];
    float cs = wave_sum_f(diff * diff);
    if (lane == 0) curvs = cs;
  }
  __syncthreads();

  for (int k = wid; k < KNNK; k += 4) {
    const int nb = ki[i * KNNK + k];
    float v[8];
    float ss = 0.f;
#pragma unroll
    for (int c = 0; c < 8; ++c) {
      const int d0 = lane + 64 * c;
      v[c] = E[(size_t)nb * DIM + d0] - ei[d0];
      ss = fmaf(v[c], v[c], ss);
    }
    ss = wave_sum_f(ss);
    const float inv = 1.0f / fmaxf(sqrtf(ss), 1e-8f);
#pragma unroll
    for (int c = 0; c < 8; ++c) vh[k * DIM + lane + 64 * c] = v[c] * inv;
  }
  __syncthreads();

  for (int p = wid; p < NPAIR; p += 4) {
    int a = 0, pp = p, cnt = 14;
    while (pp >= cnt) { pp -= cnt; cnt--; a++; }
    const int b = a + 1 + pp;
    float s = 0.f;
#pragma unroll
    for (int c = 0; c < 8; ++c) {
      const int d0 = lane + 64 * c;
      s = fmaf(vh[a * DIM + d0], vh[b * DIM + d0], s);
    }
    s = wave_sum_f(s);
    if (lane == 0) cosb[p] = s;
  }
  if (tid < 128 - NPAIR) cosb[NPAIR + tid] = CINF;
  __syncthreads();

  for (int k = 2; k <= 128; k <<= 1) {
    for (int j = k >> 1; j > 0; j >>= 1) {
      if (tid < 128) {
        const int ixj = tid ^ j;
        if (ixj > tid) {
          const bool up = ((tid & k) == 0);
          const float x = cosb[tid], y = cosb[ixj];
          if ((x > y) == up) { cosb[tid] = y; cosb[ixj] = x; }
        }
      }
      __syncthreads();
    }
  }

  float part = 0.f;
  if (tid < NPAIR) {
    const float dd = cosb[tid] - refa[(size_t)i * NPAIR + tid];
    part = dd * dd;
  }
  part = wave_sum_f(part);
  if (lane == 0) red[wid] = part;
  __syncthreads();
  if (tid == 0) {
    const float ang = red[0] + red[1] + red[2] + red[3];
    atomicAdd(&acc[0], (double)curvs);
    atomicAdd(&acc[1], (double)ang);
  }
}

// ---------------------------------------------------------------- fin
__global__ void fin_kernel(const double* __restrict__ acc,
                           float* __restrict__ out) {
  if (threadIdx.x == 0 && blockIdx.x == 0) {
    const double curv = acc[0] / ((double)NPTS * (double)KNNK);
    const double ang  = acc[1] / ((double)NPTS * (double)NPAIR);
    out[0] = (float)(0.3 * curv + 0.7 * ang);
  }
}

// ---------------------------------------------------------------- launch
extern "C" void kernel_launch(void* const* d_in, const int* in_sizes, int n_in,
                              void* d_out, int out_size, void* d_ws,
                              size_t ws_size, hipStream_t stream) {
  const float* E    = (const float*)d_in[0];
  const float* refc = (const float*)d_in[1];
  const float* refa = (const float*)d_in[2];
  float* out = (float*)d_out;

  char* ws = (char*)d_ws;
  double* acc = (double*)ws;                          // 16 B
  float*  sqn = (float*)(ws + 1024);                  // 32 KB
  float*  kd  = (float*)(ws + 33792);                 // 480 KB
  int*    ki  = (int*)(ws + 525312);                  // 480 KB
  ushort* Ehi = (ushort*)(ws + 1048576);              // 8 MB
  ushort* Elo = (ushort*)(ws + 9437184);              // 8 MB
  float*  cd  = (float*)(ws + 17825792);              // 3.75 MB
  int*    ci  = (int*)(ws + 21757952);                // 3.75 MB (end ~24.5 MB)

  hipMemsetAsync(ws, 0, 16, stream);
  prep_kernel<<<NPTS / 4, 256, 0, stream>>>(E, sqn, Ehi, Elo);
  knn_kernel<<<dim3(NPTS / NI, NJSPLIT), 256, 0, stream>>>(Ehi, Elo, sqn, cd, ci);
  kmerge_kernel<<<NPTS / 4, 256, 0, stream>>>(cd, ci, kd, ki);
  sig_kernel<<<NPTS, 256, 0, stream>>>(E, kd, ki, refc, refa, acc);
  fin_kernel<<<1, 64, 0, stream>>>(acc, out);
}

// Round 3
// 622.241 us; speedup vs baseline: 4.5602x; 1.2230x over previous
//
#include <hip/hip_runtime.h>
#include <hip/hip_bf16.h>
#include <math.h>

#define NPTS  8192
#define DIM   512
#define KNNK  15
#define NPAIR 105
#define CINF  3.0e38f

// knn tiling
#define NI      128
#define NJSPLIT 8
#define NJ      (NPTS/NJSPLIT)   // 1024
#define JS      128
#define NSUB    (NJ/JS)          // 8
#define BK      32
#define NCH     (DIM/BK)         // 16
#define DSTRIDE 130              // sdist stride: write banks (8q+m)%32 -> 2-way, scan (L+2q)%32 -> 2-way (free)

// knn LDS byte map: sdist[128][130] aliases the two 32KB staging buffers
#define BUF0_OFF   0
#define BUF1_OFF   33280
#define EXI_OFF    66560
#define SQJ_OFF    67072
#define TLS_OFF    71168
#define KNN_LDS    72192

#define VSTR 520                 // sig: V row stride (ushorts); 16B-aligned rows

typedef __attribute__((ext_vector_type(8))) short short8;
typedef __attribute__((ext_vector_type(4))) float f32x4;

static __device__ __forceinline__ float wave_sum_f(float v) {
#pragma unroll
  for (int m = 32; m > 0; m >>= 1) v += __shfl_xor(v, m, 64);
  return v;
}

static __device__ __forceinline__ void load_lds16(const void* g, void* l) {
  __builtin_amdgcn_global_load_lds(
      (const __attribute__((address_space(1))) void*)g,
      (__attribute__((address_space(3))) void*)l, 16, 0, 0);
}

static __device__ __forceinline__ void bf16split(float x, short& h, short& l) {
  __hip_bfloat16 hb = __float2bfloat16(x);
  const float hf = __bfloat162float(hb);
  __hip_bfloat16 lb = __float2bfloat16(x - hf);
  h = *(short*)&hb;
  l = *(short*)&lb;
}

// ---------------------------------------------------------------- prep
__global__ __launch_bounds__(256) void prep_kernel(
    const float* __restrict__ E, float* __restrict__ sqn,
    ushort* __restrict__ Ehi, ushort* __restrict__ Elo) {
  const int row  = blockIdx.x * 4 + (threadIdx.x >> 6);
  const int lane = threadIdx.x & 63;
  float s = 0.f;
#pragma unroll
  for (int c = 0; c < 8; ++c) {
    const int d0 = lane + 64 * c;
    const float x = E[(size_t)row * DIM + d0];
    s = fmaf(x, x, s);
    short h, l;
    bf16split(x, h, l);
    Ehi[(size_t)row * DIM + d0] = (ushort)h;
    Elo[(size_t)row * DIM + d0] = (ushort)l;
  }
  s = wave_sum_f(s);
  if (lane == 0) sqn[row] = s;
}

// ---------------------------------------------------------------- knn
// grid (8,64): blockIdx.x = j-split (-> XCD affinity), blockIdx.y = i-tile.
// Double-buffered global_load_lds staging, 1 barrier per K-chunk.
__global__ __launch_bounds__(256, 2) void knn_kernel(
    const ushort* __restrict__ Ehi, const ushort* __restrict__ Elo,
    const float* __restrict__ sqn,
    float* __restrict__ cd, int* __restrict__ ci) {
  __shared__ __align__(16) char sm[KNN_LDS];
  float* sdist = (float*)sm;
  float* exi   = (float*)(sm + EXI_OFF);
  float* sqjs  = (float*)(sm + SQJ_OFF);
  float* tls   = (float*)(sm + TLS_OFF);

  const int tid = threadIdx.x;
  const int w   = tid >> 6;
  const int L   = tid & 63;
  const int wr  = w >> 1;
  const int wc  = w & 1;
  const int jsplit = blockIdx.x;
  const int i0  = blockIdx.y * NI;
  const int j0  = jsplit * NJ;

  if (tid < 32) ((float4*)exi)[tid] = ((const float4*)(sqn + i0))[tid];
  ((float4*)sqjs)[tid] = ((const float4*)(sqn + j0))[tid];
  tls[tid] = CINF;

  const ushort* srcBase = (w & 1) ? Elo : Ehi;   // tiles: 0=Ahi 1=Alo 2=Bhi 3=Blo
  const int lrow = L >> 2;
  const int lk8  = (L & 3) * 8;

  const int myrow = tid >> 1;
  const int h     = tid & 1;
  const int gi    = i0 + myrow;

  float td[15]; int tj[15];
#pragma unroll
  for (int p = 0; p < 15; ++p) { td[p] = CINF; tj[p] = -1; }

  __syncthreads();

  // exi values this thread needs (subtile-invariant)
  float exir[4][4];
#pragma unroll
  for (int fr = 0; fr < 4; ++fr)
#pragma unroll
    for (int r = 0; r < 4; ++r)
      exir[fr][r] = exi[wr * 64 + fr * 16 + (L >> 4) * 4 + r];

  for (int js = 0; js < NSUB; ++js) {
    const int jrow0 = j0 + js * JS;
    const int trow0 = (w < 2) ? i0 : jrow0;
    const ushort* gbase = srcBase + (size_t)(trow0 + lrow) * DIM + lk8;

    f32x4 acc[4][4];
#pragma unroll
    for (int fr = 0; fr < 4; ++fr)
#pragma unroll
      for (int fc = 0; fc < 4; ++fc)
#pragma unroll
        for (int r = 0; r < 4; ++r) acc[fr][fc][r] = 0.f;

    // prologue: stage chunk 0 into buf0
    {
      char* lp = sm + BUF0_OFF + w * 8192;
#pragma unroll
      for (int s = 0; s < 8; ++s)
        load_lds16(gbase + (size_t)s * 16 * DIM, lp + s * 1024);
    }
    __syncthreads();

#pragma unroll 2
    for (int ch = 0; ch < NCH; ++ch) {
      const int cb = (ch & 1) ? BUF1_OFF : BUF0_OFF;
      const int nbo = (ch & 1) ? BUF0_OFF : BUF1_OFF;
      if (ch < NCH - 1) {
        char* lp = sm + nbo + w * 8192;
        const ushort* gp = gbase + (ch + 1) * BK;
#pragma unroll
        for (int s = 0; s < 8; ++s)
          load_lds16(gp + (size_t)s * 16 * DIM, lp + s * 1024);
      }

      const ushort* sAhi = (const ushort*)(sm + cb);
      const ushort* sAlo = (const ushort*)(sm + cb + 8192);
      const ushort* sBhi = (const ushort*)(sm + cb + 16384);
      const ushort* sBlo = (const ushort*)(sm + cb + 24576);

      short8 ah[4], al[4], bh[4], bl[4];
      const int q16 = (L >> 4) * 8;
#pragma unroll
      for (int f = 0; f < 4; ++f) {
        const int ra = f * 16 + (L & 15);
        ah[f] = *(const short8*)&sAhi[(wr * 64 + ra) * BK + q16];
        al[f] = *(const short8*)&sAlo[(wr * 64 + ra) * BK + q16];
        bh[f] = *(const short8*)&sBhi[(wc * 64 + ra) * BK + q16];
        bl[f] = *(const short8*)&sBlo[(wc * 64 + ra) * BK + q16];
      }
#pragma unroll
      for (int fr = 0; fr < 4; ++fr)
#pragma unroll
        for (int fc = 0; fc < 4; ++fc) {
          acc[fr][fc] = __builtin_amdgcn_mfma_f32_16x16x32_bf16(ah[fr], bh[fc], acc[fr][fc], 0, 0, 0);
          acc[fr][fc] = __builtin_amdgcn_mfma_f32_16x16x32_bf16(ah[fr], bl[fc], acc[fr][fc], 0, 0, 0);
          acc[fr][fc] = __builtin_amdgcn_mfma_f32_16x16x32_bf16(al[fr], bh[fc], acc[fr][fc], 0, 0, 0);
        }
      __syncthreads();   // drains next-chunk staging; orders buffer reuse
    }

    // ---- distances -> sdist
    float sqjv[4];
#pragma unroll
    for (int fc = 0; fc < 4; ++fc)
      sqjv[fc] = sqjs[js * 128 + wc * 64 + fc * 16 + (L & 15)];
#pragma unroll
    for (int fr = 0; fr < 4; ++fr)
#pragma unroll
      for (int fc = 0; fc < 4; ++fc)
#pragma unroll
        for (int r = 0; r < 4; ++r) {
          const int row_l = wr * 64 + fr * 16 + (L >> 4) * 4 + r;
          const int col_l = wc * 64 + fc * 16 + (L & 15);
          sdist[row_l * DSTRIDE + col_l] =
              exir[fr][r] + sqjv[fc] - 2.0f * acc[fr][fc][r];
        }
    __syncthreads();

    // ---- tau + self-poke + scan
    const float tau = fminf(tls[myrow * 2], tls[myrow * 2 + 1]);
    const int selfc = gi - jrow0;
    if (selfc >= 0 && selfc < JS && (selfc & 1) == h)
      sdist[myrow * DSTRIDE + selfc] = CINF;

    const float* rp = sdist + myrow * DSTRIDE + h;
    float guard = fminf(tau, td[14]);
    const int jbase = jrow0 + h;
#pragma unroll 4
    for (int q = 0; q < 64; ++q) {
      const float dd = rp[2 * q];
      if (dd < guard) {
        float cdv = dd; int cjv = jbase + 2 * q;
#pragma unroll
        for (int p = 0; p < 15; ++p) {
          const bool lt = cdv < td[p];
          const float vmin = lt ? cdv : td[p];
          const float vmax = lt ? td[p] : cdv;
          const int imin = lt ? cjv : tj[p];
          const int imax = lt ? tj[p] : cjv;
          td[p] = vmin; tj[p] = imin; cdv = vmax; cjv = imax;
        }
        guard = fminf(tau, td[14]);
      }
    }
    tls[myrow * 2 + h] = td[14];
    __syncthreads();
  }

  // ---- pair-merge -> top-15 per (row, split)
  float* md  = sdist;
  int*   mi_ = (int*)(sm + 16384);
#pragma unroll
  for (int p = 0; p < 15; ++p) {
    md[(myrow * 2 + h) * 15 + p]  = td[p];
    mi_[(myrow * 2 + h) * 15 + p] = tj[p];
  }
  __syncthreads();
  if (h == 0) {
    const float* da = &md[(myrow * 2 + 0) * 15];
    const float* db = &md[(myrow * 2 + 1) * 15];
    const int*   ia = &mi_[(myrow * 2 + 0) * 15];
    const int*   ib = &mi_[(myrow * 2 + 1) * 15];
    int pa = 0, pb = 0;
    const size_t base = ((size_t)gi * NJSPLIT + jsplit) * KNNK;
    for (int s2 = 0; s2 < KNNK; ++s2) {
      const float va = da[pa], vb = db[pb];
      if (va <= vb) { cd[base + s2] = va; ci[base + s2] = ia[pa]; ++pa; }
      else          { cd[base + s2] = vb; ci[base + s2] = ib[pb]; ++pb; }
    }
  }
}

// ---------------------------------------------------------------- merge
__global__ __launch_bounds__(256) void kmerge_kernel(
    const float* __restrict__ cd, const int* __restrict__ ci,
    float* __restrict__ kd, int* __restrict__ ki) {
  const int row = blockIdx.x * 4 + (threadIdx.x >> 6);
  const int L   = threadIdx.x & 63;
  const size_t base = (size_t)row * (NJSPLIT * KNNK);
  float v0 = (L < 120)      ? cd[base + L]      : CINF;
  float v1 = (L + 64 < 120) ? cd[base + L + 64] : CINF;
  int   i0v = (L < 120)      ? ci[base + L]      : -1;
  int   i1v = (L + 64 < 120) ? ci[base + L + 64] : -1;
  for (int sel = 0; sel < KNNK; ++sel) {
    float v; int idx, slot;
    if (v1 < v0) { v = v1; idx = i1v; slot = (L << 1) | 1; }
    else         { v = v0; idx = i0v; slot = (L << 1); }
#pragma unroll
    for (int off = 32; off > 0; off >>= 1) {
      const float ov = __shfl_down(v, off, 64);
      const int   oi = __shfl_down(idx, off, 64);
      const int   os = __shfl_down(slot, off, 64);
      if (ov < v) { v = ov; idx = oi; slot = os; }
    }
    const float vmin = __shfl(v, 0, 64);
    const int   imin = __shfl(idx, 0, 64);
    const int   smin = __shfl(slot, 0, 64);
    if (L == (smin >> 1)) { if (smin & 1) v1 = CINF; else v0 = CINF; }
    if (L == 0) {
      kd[row * KNNK + sel] = sqrtf(fmaxf(vmin, 1e-12f));
      ki[row * KNNK + sel] = imin;
    }
  }
}

// ---------------------------------------------------------------- sig
// Per point: normalized neighbor vectors (bf16 hi/lo) in LDS, 15x15 gram
// via split-bf16 MFMA (K-split across 4 waves), bitonic sort, loss.
__global__ __launch_bounds__(256) void sig_kernel(
    const float* __restrict__ E, const float* __restrict__ kd,
    const int* __restrict__ ki, const float* __restrict__ refc,
    const float* __restrict__ refa, double* __restrict__ acc) {
  __shared__ __align__(16) float ei[DIM];
  __shared__ __align__(16) ushort vhi[16 * VSTR];
  __shared__ __align__(16) ushort vlo[16 * VSTR];
  __shared__ float gp[4 * 256];
  __shared__ float cosb[128];
  __shared__ float red[4];
  __shared__ float curvs;

  const int i   = blockIdx.x;
  const int tid = threadIdx.x;
  const int wid = tid >> 6;
  const int L   = tid & 63;

  ((float2*)ei)[tid] = ((const float2*)(E + (size_t)i * DIM))[tid];

  if (wid == 0) {
    float d = (L < KNNK) ? kd[i * KNNK + L] : 0.f;
    float tot = wave_sum_f(d);
    float mean_d = tot / (float)KNNK + 1e-8f;
    float diff = (L < KNNK) ? (d / mean_d - refc[i * KNNK + L]) : 0.f;
    float cs = wave_sum_f(diff * diff);
    if (L == 0) curvs = cs;
  }
  __syncthreads();

  // normalized neighbor vectors -> bf16 hi/lo rows (row 15 = zeros)
#pragma unroll
  for (int t = 0; t < 4; ++t) {
    const int k = wid + 4 * t;
    float v[8];
    if (k < KNNK) {
      const int nb = ki[i * KNNK + k];
      const float4 ga = ((const float4*)(E + (size_t)nb * DIM))[L * 2];
      const float4 gb = ((const float4*)(E + (size_t)nb * DIM))[L * 2 + 1];
      const float4 ea = ((const float4*)ei)[L * 2];
      const float4 eb = ((const float4*)ei)[L * 2 + 1];
      v[0] = ga.x - ea.x; v[1] = ga.y - ea.y; v[2] = ga.z - ea.z; v[3] = ga.w - ea.w;
      v[4] = gb.x - eb.x; v[5] = gb.y - eb.y; v[6] = gb.z - eb.z; v[7] = gb.w - eb.w;
      float ss = 0.f;
#pragma unroll
      for (int c = 0; c < 8; ++c) ss = fmaf(v[c], v[c], ss);
      ss = wave_sum_f(ss);
      const float inv = 1.0f / fmaxf(sqrtf(ss), 1e-8f);
#pragma unroll
      for (int c = 0; c < 8; ++c) v[c] *= inv;
    } else {
#pragma unroll
      for (int c = 0; c < 8; ++c) v[c] = 0.f;
    }
    short8 H, Lo;
#pragma unroll
    for (int c = 0; c < 8; ++c) {
      short hh, ll;
      bf16split(v[c], hh, ll);
      H[c] = hh; Lo[c] = ll;
    }
    *(short8*)&vhi[k * VSTR + L * 8] = H;
    *(short8*)&vlo[k * VSTR + L * 8] = Lo;
  }
  __syncthreads();

  // gram: wave wid handles K-chunks 4*wid .. 4*wid+3
  {
    f32x4 gA, gB;
#pragma unroll
    for (int r = 0; r < 4; ++r) { gA[r] = 0.f; gB[r] = 0.f; }
    const int m  = L & 15;
    const int q8 = (L >> 4) * 8;
#pragma unroll
    for (int c = 0; c < 4; ++c) {
      const int k0 = (wid * 4 + c) * 32;
      const short8 vh_ = *(const short8*)&vhi[m * VSTR + k0 + q8];
      const short8 vl_ = *(const short8*)&vlo[m * VSTR + k0 + q8];
      gA = __builtin_amdgcn_mfma_f32_16x16x32_bf16(vh_, vh_, gA, 0, 0, 0);
      gB = __builtin_amdgcn_mfma_f32_16x16x32_bf16(vh_, vl_, gB, 0, 0, 0);
      gB = __builtin_amdgcn_mfma_f32_16x16x32_bf16(vl_, vh_, gB, 0, 0, 0);
    }
    f32x4 g = gA + gB;
    *(f32x4*)&gp[wid * 256 + L * 4] = g;
  }
  __syncthreads();

  // reduce partials + extract upper triangle
  {
    const float v = gp[tid] + gp[256 + tid] + gp[512 + tid] + gp[768 + tid];
    const int col = (tid >> 2) & 15;
    const int row = ((tid >> 6) << 2) + (tid & 3);
    if (row < col && col < KNNK) {
      const int p = row * (29 - row) / 2 + (col - row - 1);
      cosb[p] = v;
    }
    if (tid < 128 - NPAIR) cosb[NPAIR + tid] = CINF;
  }
  __syncthreads();

  // bitonic sort 128 ascending
  for (int k = 2; k <= 128; k <<= 1) {
    for (int j = k >> 1; j > 0; j >>= 1) {
      if (tid < 128) {
        const int ixj = tid ^ j;
        if (ixj > tid) {
          const bool up = ((tid & k) == 0);
          const float x = cosb[tid], y = cosb[ixj];
          if ((x > y) == up) { cosb[tid] = y; cosb[ixj] = x; }
        }
      }
      __syncthreads();
    }
  }

  float part = 0.f;
  if (tid < NPAIR) {
    const float dd = cosb[tid] - refa[(size_t)i * NPAIR + tid];
    part = dd * dd;
  }
  part = wave_sum_f(part);
  if (L == 0) red[wid] = part;
  __syncthreads();
  if (tid == 0) {
    const float ang = red[0] + red[1] + red[2] + red[3];
    atomicAdd(&acc[0], (double)curvs);
    atomicAdd(&acc[1], (double)ang);
  }
}

// ---------------------------------------------------------------- fin
__global__ void fin_kernel(const double* __restrict__ acc,
                           float* __restrict__ out) {
  if (threadIdx.x == 0 && blockIdx.x == 0) {
    const double curv = acc[0] / ((double)NPTS * (double)KNNK);
    const double ang  = acc[1] / ((double)NPTS * (double)NPAIR);
    out[0] = (float)(0.3 * curv + 0.7 * ang);
  }
}

// ---------------------------------------------------------------- launch
extern "C" void kernel_launch(void* const* d_in, const int* in_sizes, int n_in,
                              void* d_out, int out_size, void* d_ws,
                              size_t ws_size, hipStream_t stream) {
  const float* E    = (const float*)d_in[0];
  const float* refc = (const float*)d_in[1];
  const float* refa = (const float*)d_in[2];
  float* out = (float*)d_out;

  char* ws = (char*)d_ws;
  double* acc = (double*)ws;
  float*  sqn = (float*)(ws + 1024);
  float*  kd  = (float*)(ws + 33792);
  int*    ki  = (int*)(ws + 525312);
  ushort* Ehi = (ushort*)(ws + 1048576);
  ushort* Elo = (ushort*)(ws + 9437184);
  float*  cd  = (float*)(ws + 17825792);
  int*    ci  = (int*)(ws + 21757952);

  hipMemsetAsync(ws, 0, 16, stream);
  prep_kernel<<<NPTS / 4, 256, 0, stream>>>(E, sqn, Ehi, Elo);
  knn_kernel<<<dim3(NJSPLIT, NPTS / NI), 256, 0, stream>>>(Ehi, Elo, sqn, cd, ci);
  kmerge_kernel<<<NPTS / 4, 256, 0, stream>>>(cd, ci, kd, ki);
  sig_kernel<<<NPTS, 256, 0, stream>>>(E, kd, ki, refc, refa, acc);
  fin_kernel<<<1, 64, 0, stream>>>(acc, out);
}